// Round 6
// baseline (622.085 us; speedup 1.0000x reference)
//
#include <hip/hip_runtime.h>
#include <hip/hip_bf16.h>
#include <hip/hip_fp8.h>

#define M_N  100000
#define N_E  1600000
#define FEAT 256
#define NCLS 64
#define SCAN_NB ((M_N + 255) / 256)   // 391 blocks

typedef __attribute__((ext_vector_type(8))) short bf16x8;
typedef __attribute__((ext_vector_type(8))) ushort u16x8;
typedef __attribute__((ext_vector_type(4))) float f32x4;
typedef unsigned char uchar;

__device__ __forceinline__ ushort f2bf(float f) {
    __hip_bfloat16 h = __float2bfloat16(f);
    return __builtin_bit_cast(ushort, h);
}
__device__ __forceinline__ void load_lds16(const void* g, void* l) {
    __builtin_amdgcn_global_load_lds(
        (const __attribute__((address_space(1))) void*)g,
        (__attribute__((address_space(3))) void*)l, 16, 0, 0);
}
// e4m3fn fast decode (4 ops): exact for normals; zero/subnormal (|v|<2^-6,
// ~1.7% of values) approximated as (1+M/8)*2^-7 — error <2^-7 per elem,
// vanishes in the 16-edge sum + 100k-node mean (est. <1e-4 at output).
__device__ __forceinline__ float fp8f(uint b) {
    b &= 0xffu;
    uint bits = ((b & 0x80u) << 24) | (((b & 0x7fu) << 20) + 0x3C000000u);
    return __uint_as_float(bits);
}

// ---------------- degree histogram (int atomics) --------------------------
__global__ void deg_kernel(const int* __restrict__ src, const int* __restrict__ dst,
                           int* __restrict__ cnt_out, int* __restrict__ cnt_in, int nE) {
    int i = blockIdx.x * blockDim.x + threadIdx.x;
    int stride = gridDim.x * blockDim.x;
    for (int e = i; e < nE; e += stride) {
        atomicAdd(&cnt_out[src[e]], 1);
        atomicAdd(&cnt_in[dst[e]], 1);
    }
}

// ---------------- scan phase A: per-block sums of cnt_in ------------------
__global__ __launch_bounds__(256) void scanA_kernel(const int* __restrict__ cnt_in,
                                                    int* __restrict__ bsum) {
    __shared__ int sh[256];
    int t = threadIdx.x;
    int i = blockIdx.x * 256 + t;
    sh[t] = (i < M_N) ? cnt_in[i] : 0;
    __syncthreads();
#pragma unroll
    for (int o = 128; o > 0; o >>= 1) {
        if (t < o) sh[t] += sh[t + o];
        __syncthreads();
    }
    if (t == 0) bsum[blockIdx.x] = sh[0];
}

// ---------------- scan phase B: exclusive scan of 391 partials ------------
__global__ __launch_bounds__(512) void scanB_kernel(int* __restrict__ bsum) {
    __shared__ int sh[512];
    int t = threadIdx.x;
    int v = (t < SCAN_NB) ? bsum[t] : 0;
    sh[t] = v;
    __syncthreads();
    for (int o = 1; o < 512; o <<= 1) {
        int u = (t >= o) ? sh[t - o] : 0;
        __syncthreads();
        sh[t] += u;
        __syncthreads();
    }
    if (t < SCAN_NB) bsum[t] = sh[t] - v;   // exclusive offsets, in place
}

// ---------------- scan phase C: row_start + cursor + rs_out ---------------
__global__ __launch_bounds__(256) void scanC_kernel(
    const int* __restrict__ cnt_in, const int* __restrict__ cnt_out,
    const int* __restrict__ bsum, int* __restrict__ row_start,
    int* __restrict__ cursor, float* __restrict__ rs_out) {
    __shared__ int sh[256];
    int t = threadIdx.x;
    int i = blockIdx.x * 256 + t;
    int v = (i < M_N) ? cnt_in[i] : 0;
    sh[t] = v;
    __syncthreads();
    for (int o = 1; o < 256; o <<= 1) {
        int u = (t >= o) ? sh[t - o] : 0;
        __syncthreads();
        sh[t] += u;
        __syncthreads();
    }
    int base = bsum[blockIdx.x];
    int excl = base + sh[t] - v;
    if (i < M_N) {
        row_start[i] = excl;
        cursor[i]    = excl;
        int co = cnt_out[i]; if (co < 1) co = 1;
        rs_out[i] = rsqrtf((float)co);
        if (i == M_N - 1) row_start[M_N] = excl + v;
    }
}

// ---------------- bucket scatter: src ids grouped by dst ------------------
__global__ void bucket_kernel(const int* __restrict__ src, const int* __restrict__ dst,
                              int* __restrict__ cursor, int* __restrict__ csr_src, int nE) {
    int i = blockIdx.x * blockDim.x + threadIdx.x;
    int stride = gridDim.x * blockDim.x;
    for (int e = i; e < nE; e += stride) {
        int pos = atomicAdd(&cursor[dst[e]], 1);
        csr_src[pos] = src[e];
    }
}

// ---------------- Wt = bf16(W^T)  [n][k] ----------------------------------
__global__ void wt_kernel(const float* __restrict__ W, ushort* __restrict__ Wt) {
    int i = blockIdx.x * blockDim.x + threadIdx.x;
    if (i < FEAT * FEAT) {
        int k = i >> 8, n = i & 255;
        Wt[n * FEAT + k] = f2bf(W[i]);
    }
}

// ---------------- MFMA GEMM: xw = fp8((x*rs_out) @ W), fused norm+cvt -----
// 128x128 tile, BK=32, 4 waves (2x2), each wave 64x64 via 4x4 16x16x32 frags.
// A-tile: reg-staged from f32 x, scaled by rs_out[row], converted to bf16.
// B-tile: global_load_lds from pre-transposed bf16 Wt. C stored as fp8 e4m3.
__global__ __launch_bounds__(256) void gemm_xw_kernel(
    const float* __restrict__ x, const float* __restrict__ rs_out,
    const ushort* __restrict__ Wt, uchar* __restrict__ xw8) {
    __shared__ ushort As[128 * 32];   // 8KB, rows of 64B (k-minor)
    __shared__ ushort Bs[128 * 32];   // 8KB, n-major k-minor (transposed W)
    const int tid  = threadIdx.x;
    const int lane = tid & 63;
    const int w    = tid >> 6;
    const int wr   = w >> 1, wc = w & 1;
    const int m0   = blockIdx.x * 128;
    const int n0   = blockIdx.y * 128;

    // A staging coords: thread -> (row, 16-feat half)
    const int ar = tid >> 1;                 // 0..127
    const int ah = tid & 1;                  // 0..1
    int arow = m0 + ar; if (arow >= M_N) arow = M_N - 1;   // clamp (C-write guarded)
    const float rsA = rs_out[arow];
    const float* xrow = x + (size_t)arow * FEAT + ah * 16;

    // B staging coords (global_load_lds: wave-uniform base + lane*16)
    const int lr = lane >> 2;                // 16 rows per 1KB segment
    const int lb = (lane & 3) * 16;          // byte within 64B row

    f32x4 acc[4][4];
#pragma unroll
    for (int i = 0; i < 4; ++i)
#pragma unroll
        for (int j = 0; j < 4; ++j) {
            acc[i][j][0] = 0.f; acc[i][j][1] = 0.f;
            acc[i][j][2] = 0.f; acc[i][j][3] = 0.f;
        }

    for (int k0 = 0; k0 < FEAT; k0 += 32) {
        __syncthreads();               // LDS consumed by previous iter
        // B: 8 segments of 1KB, 2 per wave
#pragma unroll
        for (int j = 0; j < 2; ++j) {
            const int seg = (w * 2 + j) * 1024;
            int row = (seg >> 6) + lr;
            load_lds16((const char*)Wt + (size_t)(n0 + row) * 512 + k0 * 2 + lb,
                       (char*)Bs + seg);
        }
        // A: reg-stage 16 f32, scale, convert, 32B ds_write
        float4 f0 = *(const float4*)(xrow + k0 + 0);
        float4 f1 = *(const float4*)(xrow + k0 + 4);
        float4 f2 = *(const float4*)(xrow + k0 + 8);
        float4 f3 = *(const float4*)(xrow + k0 + 12);
        u16x8 lo, hi;
        lo[0] = f2bf(f0.x * rsA); lo[1] = f2bf(f0.y * rsA);
        lo[2] = f2bf(f0.z * rsA); lo[3] = f2bf(f0.w * rsA);
        lo[4] = f2bf(f1.x * rsA); lo[5] = f2bf(f1.y * rsA);
        lo[6] = f2bf(f1.z * rsA); lo[7] = f2bf(f1.w * rsA);
        hi[0] = f2bf(f2.x * rsA); hi[1] = f2bf(f2.y * rsA);
        hi[2] = f2bf(f2.z * rsA); hi[3] = f2bf(f2.w * rsA);
        hi[4] = f2bf(f3.x * rsA); hi[5] = f2bf(f3.y * rsA);
        hi[6] = f2bf(f3.z * rsA); hi[7] = f2bf(f3.w * rsA);
        *(u16x8*)((char*)As + ar * 64 + ah * 32)      = lo;
        *(u16x8*)((char*)As + ar * 64 + ah * 32 + 16) = hi;
        __syncthreads();               // drains vmcnt+lgkmcnt (compiler inserts)

        bf16x8 a[4], b[4];
#pragma unroll
        for (int mi = 0; mi < 4; ++mi) {
            int row = wr * 64 + mi * 16 + (lane & 15);
            a[mi] = *(const bf16x8*)((const char*)As + row * 64 + (lane >> 4) * 16);
        }
#pragma unroll
        for (int ni = 0; ni < 4; ++ni) {
            int n = wc * 64 + ni * 16 + (lane & 15);
            b[ni] = *(const bf16x8*)((const char*)Bs + n * 64 + (lane >> 4) * 16);
        }
#pragma unroll
        for (int mi = 0; mi < 4; ++mi)
#pragma unroll
            for (int ni = 0; ni < 4; ++ni)
                acc[mi][ni] = __builtin_amdgcn_mfma_f32_16x16x32_bf16(
                    a[mi], b[ni], acc[mi][ni], 0, 0, 0);
    }

    // C/D layout: col = lane&15, row = (lane>>4)*4 + j   [m89/m91 verified]
#pragma unroll
    for (int mi = 0; mi < 4; ++mi) {
        int rbase = m0 + wr * 64 + mi * 16 + (lane >> 4) * 4;
#pragma unroll
        for (int ni = 0; ni < 4; ++ni) {
            int col = n0 + wc * 64 + ni * 16 + (lane & 15);
#pragma unroll
            for (int j = 0; j < 4; ++j) {
                int r = rbase + j;
                if (r < M_N) {
                    __hip_fp8_e4m3 q(acc[mi][ni][j]);   // hw RNE + satfinite
                    xw8[(size_t)r * FEAT + col] = q.__x;
                }
            }
        }
    }
}

// ---------------- gather + epilogue + pool (fp8 rows, range [d_lo,d_hi)) --
// One wave per dst row (grid-stride). lane owns feats 4l..4l+3 (one uint).
__global__ __launch_bounds__(256) void gather_pool_kernel(
    const uchar* __restrict__ xw8, const int* __restrict__ csr_src,
    const int* __restrict__ row_start, const float* __restrict__ bias,
    float* __restrict__ pooled, int d_lo, int d_hi) {
    __shared__ float pool_lds[FEAT];
    int tid = threadIdx.x;
    pool_lds[tid] = 0.0f;
    __syncthreads();
    int lane = tid & 63;
    int wave = tid >> 6;
    int gw = blockIdx.x * 4 + wave;
    int nw = gridDim.x * 4;
    float b0 = bias[lane * 4 + 0], b1 = bias[lane * 4 + 1];
    float b2 = bias[lane * 4 + 2], b3 = bias[lane * 4 + 3];
    float p0 = 0.f, p1 = 0.f, p2 = 0.f, p3 = 0.f;

    for (int d = d_lo + gw; d < d_hi; d += nw) {
        int e0 = row_start[d], e1 = row_start[d + 1];
        float s0 = 0.f, s1 = 0.f, s2 = 0.f, s3 = 0.f;
        int e = e0;
        for (; e + 3 < e1; e += 4) {
            int ia = csr_src[e], ib = csr_src[e + 1];
            int ic = csr_src[e + 2], id = csr_src[e + 3];
            uint ua = *(const uint*)(xw8 + (size_t)ia * FEAT + lane * 4);
            uint ub = *(const uint*)(xw8 + (size_t)ib * FEAT + lane * 4);
            uint uc = *(const uint*)(xw8 + (size_t)ic * FEAT + lane * 4);
            uint ud = *(const uint*)(xw8 + (size_t)id * FEAT + lane * 4);
            s0 += (fp8f(ua) + fp8f(ub)) + (fp8f(uc) + fp8f(ud));
            s1 += (fp8f(ua >> 8) + fp8f(ub >> 8)) + (fp8f(uc >> 8) + fp8f(ud >> 8));
            s2 += (fp8f(ua >> 16) + fp8f(ub >> 16)) + (fp8f(uc >> 16) + fp8f(ud >> 16));
            s3 += (fp8f(ua >> 24) + fp8f(ub >> 24)) + (fp8f(uc >> 24) + fp8f(ud >> 24));
        }
        for (; e < e1; ++e) {
            int ia = csr_src[e];
            uint ua = *(const uint*)(xw8 + (size_t)ia * FEAT + lane * 4);
            s0 += fp8f(ua); s1 += fp8f(ua >> 8);
            s2 += fp8f(ua >> 16); s3 += fp8f(ua >> 24);
        }
        float ri = rsqrtf(fmaxf((float)(e1 - e0), 1.0f));
        p0 += fmaxf(s0 * ri + b0, 0.f);
        p1 += fmaxf(s1 * ri + b1, 0.f);
        p2 += fmaxf(s2 * ri + b2, 0.f);
        p3 += fmaxf(s3 * ri + b3, 0.f);
    }
    atomicAdd(&pool_lds[lane * 4 + 0], p0);
    atomicAdd(&pool_lds[lane * 4 + 1], p1);
    atomicAdd(&pool_lds[lane * 4 + 2], p2);
    atomicAdd(&pool_lds[lane * 4 + 3], p3);
    __syncthreads();
    atomicAdd(&pooled[tid], pool_lds[tid]);
}

// ---------------- (pooled/N) @ W2 + b2 -> softmax(64) ---------------------
__global__ void final_kernel(const float* __restrict__ pooled, const float* __restrict__ W2,
                             const float* __restrict__ b2, float* __restrict__ out) {
    int c = threadIdx.x;  // 64 threads = one wave
    const float invN = 1.0f / (float)M_N;
    float acc = 0.0f;
    for (int f = 0; f < FEAT; ++f) acc += pooled[f] * W2[f * NCLS + c];
    acc = acc * invN + b2[c];
    float m = acc;
#pragma unroll
    for (int o = 32; o > 0; o >>= 1) m = fmaxf(m, __shfl_xor(m, o));
    float e = expf(acc - m);
    float s = e;
#pragma unroll
    for (int o = 32; o > 0; o >>= 1) s += __shfl_xor(s, o);
    out[c] = e / s;
}

extern "C" void kernel_launch(void* const* d_in, const int* in_sizes, int n_in,
                              void* d_out, int out_size, void* d_ws, size_t ws_size,
                              hipStream_t stream) {
    const float* x   = (const float*)d_in[0];
    const int*   src = (const int*)d_in[1];
    const int*   dst = (const int*)d_in[2];
    const float* W   = (const float*)d_in[3];
    const float* b   = (const float*)d_in[4];
    const float* W2  = (const float*)d_in[5];
    const float* b2  = (const float*)d_in[6];
    float* out = (float*)d_out;

    // workspace layout (16B-aligned sections)
    char* p = (char*)d_ws;
    uchar*  xw8      = (uchar*)p;   p += (size_t)M_N * FEAT;          // 25.6 MB
    ushort* Wt       = (ushort*)p;  p += (size_t)FEAT * FEAT * 2;     // 128 KB
    int*    cnt_out  = (int*)p;     p += (size_t)M_N * 4;             // zeroed
    int*    cnt_in   = (int*)p;     p += (size_t)M_N * 4;             // zeroed
    float*  pooled   = (float*)p;   p += 1024;                        // zeroed
    int*    row_start= (int*)p;     p += ((size_t)M_N + 8) * 4;
    int*    cursor   = (int*)p;     p += (size_t)M_N * 4;
    float*  rs_out   = (float*)p;   p += (size_t)M_N * 4;
    int*    bsum     = (int*)p;     p += 2048;                        // 391 partials
    int*    csr_src  = (int*)p;     p += (size_t)N_E * 4;

    // zero cnt_out + cnt_in + pooled (contiguous)
    hipMemsetAsync(cnt_out, 0, (size_t)(2 * M_N) * 4 + 1024, stream);

    deg_kernel<<<1024, 256, 0, stream>>>(src, dst, cnt_out, cnt_in, N_E);
    scanA_kernel<<<SCAN_NB, 256, 0, stream>>>(cnt_in, bsum);
    scanB_kernel<<<1, 512, 0, stream>>>(bsum);
    scanC_kernel<<<SCAN_NB, 256, 0, stream>>>(cnt_in, cnt_out, bsum,
                                              row_start, cursor, rs_out);
    bucket_kernel<<<1024, 256, 0, stream>>>(src, dst, cursor, csr_src, N_E);
    wt_kernel<<<(FEAT * FEAT + 255) / 256, 256, 0, stream>>>(W, Wt);
    gemm_xw_kernel<<<dim3((M_N + 127) / 128, 2), 256, 0, stream>>>(x, rs_out, Wt, xw8);
    gather_pool_kernel<<<1024, 256, 0, stream>>>(xw8, csr_src, row_start, b, pooled,
                                                 0, M_N / 2);
    gather_pool_kernel<<<1024, 256, 0, stream>>>(xw8, csr_src, row_start, b, pooled,
                                                 M_N / 2, M_N);
    final_kernel<<<1, 64, 0, stream>>>(pooled, W2, b2, out);
}

// Round 8
// 543.444 us; speedup vs baseline: 1.1447x; 1.1447x over previous
//
#include <hip/hip_runtime.h>
#include <hip/hip_bf16.h>
#include <hip/hip_fp8.h>

#define M_N  100000
#define N_E  1600000
#define FEAT 256
#define NCLS 64
#define BKT_SH 7                      // 128 dsts per coarse bucket
#define NBKT ((M_N + 127) >> BKT_SH)  // 782

typedef __attribute__((ext_vector_type(8))) short bf16x8;
typedef __attribute__((ext_vector_type(8))) ushort u16x8;
typedef __attribute__((ext_vector_type(4))) float f32x4;
typedef unsigned char uchar;

__device__ __forceinline__ ushort f2bf(float f) {
    __hip_bfloat16 h = __float2bfloat16(f);
    return __builtin_bit_cast(ushort, h);
}
__device__ __forceinline__ void load_lds16(const void* g, void* l) {
    __builtin_amdgcn_global_load_lds(
        (const __attribute__((address_space(1))) void*)g,
        (__attribute__((address_space(3))) void*)l, 16, 0, 0);
}
// e4m3fn fast decode (4 ops): exact for normals; zero/subnormal (|v|<2^-6)
// approximated as (1+M/8)*2^-7 — error <2^-7 per elem, washes out in the
// edge-sum + 100k mean (absmax 0.0 observed in round 6).
__device__ __forceinline__ float fp8f(uint b) {
    b &= 0xffu;
    uint bits = ((b & 0x80u) << 24) | (((b & 0x7fu) << 20) + 0x3C000000u);
    return __uint_as_float(bits);
}

// ---- hist: cnt_out[src]++ (global) + coarse_cnt[dst>>7]++ (LDS-staged) ----
__global__ __launch_bounds__(256) void hist_kernel(
    const int* __restrict__ src, const int* __restrict__ dst,
    int* __restrict__ cnt_out, int* __restrict__ coarse_cnt, int nE) {
    __shared__ int lh[NBKT];
    int tid = threadIdx.x;
    for (int i = tid; i < NBKT; i += 256) lh[i] = 0;
    __syncthreads();
    int i = blockIdx.x * 256 + tid;
    int stride = gridDim.x * 256;
    for (int e = i; e < nE; e += stride) {
        atomicAdd(&cnt_out[src[e]], 1);
        atomicAdd(&lh[dst[e] >> BKT_SH], 1);
    }
    __syncthreads();
    for (int i2 = tid; i2 < NBKT; i2 += 256) {
        int v = lh[i2];
        if (v) atomicAdd(&coarse_cnt[i2], v);
    }
}

// ---- cscan: exclusive scan of coarse_cnt -> cbase; init padded cursors ----
__global__ __launch_bounds__(1024) void cscan_kernel(
    const int* __restrict__ coarse_cnt, int* __restrict__ cbase,
    int* __restrict__ ccur) {
    __shared__ int sh[1024];
    int t = threadIdx.x;
    int v = (t < NBKT) ? coarse_cnt[t] : 0;
    sh[t] = v;
    __syncthreads();
    for (int o = 1; o < 1024; o <<= 1) {
        int u = (t >= o) ? sh[t - o] : 0;
        __syncthreads();
        sh[t] += u;
        __syncthreads();
    }
    if (t < NBKT) {
        int excl = sh[t] - v;
        cbase[t] = excl;
        ccur[t * 16] = excl;     // 64B-padded cursor (one line per bucket)
    }
    if (t == 0) cbase[NBKT] = N_E;
}

// ---- rs_out = rsqrt(max(out_degree,1)) -----------------------------------
__global__ void rs_kernel(const int* __restrict__ cnt_out,
                          float* __restrict__ rs_out, int n) {
    int i = blockIdx.x * blockDim.x + threadIdx.x;
    if (i < n) {
        int co = cnt_out[i]; if (co < 1) co = 1;
        rs_out[i] = rsqrtf((float)co);
    }
}

// ---- pair: coarse partition (src,dst) by dst bucket ----------------------
__global__ void pair_kernel(const int* __restrict__ src, const int* __restrict__ dst,
                            int* __restrict__ ccur, int2* __restrict__ pairs, int nE) {
    int i = blockIdx.x * blockDim.x + threadIdx.x;
    int stride = gridDim.x * blockDim.x;
    for (int e = i; e < nE; e += stride) {
        int s = src[e], d = dst[e];
        int pos = atomicAdd(&ccur[(d >> BKT_SH) * 16], 1);
        pairs[pos] = make_int2(s, d);
    }
}

// ---- lsort: per-bucket counting sort -> csr_src + row_start --------------
// One block per coarse bucket; two passes over the bucket's pairs.
__global__ __launch_bounds__(256) void lsort_kernel(
    const int2* __restrict__ pairs, const int* __restrict__ cbase,
    int* __restrict__ csr_src, int* __restrict__ row_start) {
    __shared__ int cnt[128];
    __shared__ int loc[128];
    int b = blockIdx.x;
    int t = threadIdx.x;
    int lo = cbase[b], hi = cbase[b + 1];
    int n = hi - lo;
    int d0 = b << BKT_SH;
    if (t < 128) cnt[t] = 0;
    __syncthreads();
    for (int i = t; i < n; i += 256) {
        int d = pairs[lo + i].y - d0;
        atomicAdd(&cnt[d], 1);
    }
    __syncthreads();
    // exclusive scan of cnt[128]
    int v = (t < 128) ? cnt[t] : 0;
    for (int o = 1; o < 128; o <<= 1) {
        int u = (t >= o && t < 128) ? cnt[t - o] : 0;
        __syncthreads();
        if (t < 128) cnt[t] += u;
        __syncthreads();
    }
    if (t < 128) {
        int excl = cnt[t] - v;              // exclusive prefix
        loc[t] = lo + excl;                 // global write cursor
        int d = d0 + t;
        if (d < M_N) row_start[d] = lo + excl;
    }
    if (b == NBKT - 1 && t == 0) row_start[M_N] = N_E;
    __syncthreads();
    for (int i = t; i < n; i += 256) {
        int2 p = pairs[lo + i];
        int off = atomicAdd(&loc[p.y - d0], 1);
        csr_src[off] = p.x;
    }
}

// ---------------- Wt = bf16(W^T)  [n][k] ----------------------------------
__global__ void wt_kernel(const float* __restrict__ W, ushort* __restrict__ Wt) {
    int i = blockIdx.x * blockDim.x + threadIdx.x;
    if (i < FEAT * FEAT) {
        int k = i >> 8, n = i & 255;
        Wt[n * FEAT + k] = f2bf(W[i]);
    }
}

// ---- MFMA GEMM: xw8 = fp8((x*rs_out) @ W); C staged via LDS, coalesced ---
__global__ __launch_bounds__(256) void gemm_xw_kernel(
    const float* __restrict__ x, const float* __restrict__ rs_out,
    const ushort* __restrict__ Wt, uchar* __restrict__ xw8) {
    __shared__ ushort As[128 * 32];   // 8KB
    __shared__ ushort Bs[128 * 32];   // 8KB
    __shared__ uchar  Cs[128 * 128];  // 16KB fp8 C tile
    const int tid  = threadIdx.x;
    const int lane = tid & 63;
    const int w    = tid >> 6;
    const int wr   = w >> 1, wc = w & 1;
    const int m0   = blockIdx.x * 128;
    const int n0   = blockIdx.y * 128;

    const int ar = tid >> 1;
    const int ah = tid & 1;
    int arow = m0 + ar; if (arow >= M_N) arow = M_N - 1;
    const float rsA = rs_out[arow];
    const float* xrow = x + (size_t)arow * FEAT + ah * 16;

    const int lr = lane >> 2;
    const int lb = (lane & 3) * 16;

    f32x4 acc[4][4];
#pragma unroll
    for (int i = 0; i < 4; ++i)
#pragma unroll
        for (int j = 0; j < 4; ++j) {
            acc[i][j][0] = 0.f; acc[i][j][1] = 0.f;
            acc[i][j][2] = 0.f; acc[i][j][3] = 0.f;
        }

    for (int k0 = 0; k0 < FEAT; k0 += 32) {
        __syncthreads();
#pragma unroll
        for (int j = 0; j < 2; ++j) {
            const int seg = (w * 2 + j) * 1024;
            int row = (seg >> 6) + lr;
            load_lds16((const char*)Wt + (size_t)(n0 + row) * 512 + k0 * 2 + lb,
                       (char*)Bs + seg);
        }
        float4 f0 = *(const float4*)(xrow + k0 + 0);
        float4 f1 = *(const float4*)(xrow + k0 + 4);
        float4 f2 = *(const float4*)(xrow + k0 + 8);
        float4 f3 = *(const float4*)(xrow + k0 + 12);
        u16x8 lo, hi;
        lo[0] = f2bf(f0.x * rsA); lo[1] = f2bf(f0.y * rsA);
        lo[2] = f2bf(f0.z * rsA); lo[3] = f2bf(f0.w * rsA);
        lo[4] = f2bf(f1.x * rsA); lo[5] = f2bf(f1.y * rsA);
        lo[6] = f2bf(f1.z * rsA); lo[7] = f2bf(f1.w * rsA);
        hi[0] = f2bf(f2.x * rsA); hi[1] = f2bf(f2.y * rsA);
        hi[2] = f2bf(f2.z * rsA); hi[3] = f2bf(f2.w * rsA);
        hi[4] = f2bf(f3.x * rsA); hi[5] = f2bf(f3.y * rsA);
        hi[6] = f2bf(f3.z * rsA); hi[7] = f2bf(f3.w * rsA);
        *(u16x8*)((char*)As + ar * 64 + ah * 32)      = lo;
        *(u16x8*)((char*)As + ar * 64 + ah * 32 + 16) = hi;
        __syncthreads();

        bf16x8 a[4], b[4];
#pragma unroll
        for (int mi = 0; mi < 4; ++mi) {
            int row = wr * 64 + mi * 16 + (lane & 15);
            a[mi] = *(const bf16x8*)((const char*)As + row * 64 + (lane >> 4) * 16);
        }
#pragma unroll
        for (int ni = 0; ni < 4; ++ni) {
            int nn = wc * 64 + ni * 16 + (lane & 15);
            b[ni] = *(const bf16x8*)((const char*)Bs + nn * 64 + (lane >> 4) * 16);
        }
#pragma unroll
        for (int mi = 0; mi < 4; ++mi)
#pragma unroll
            for (int ni = 0; ni < 4; ++ni)
                acc[mi][ni] = __builtin_amdgcn_mfma_f32_16x16x32_bf16(
                    a[mi], b[ni], acc[mi][ni], 0, 0, 0);
    }

    // fp8 quantize into LDS tile (C/D: col=lane&15, row=(lane>>4)*4+j)
#pragma unroll
    for (int mi = 0; mi < 4; ++mi) {
        int rl = wr * 64 + mi * 16 + (lane >> 4) * 4;
#pragma unroll
        for (int ni = 0; ni < 4; ++ni) {
            int cl = wc * 64 + ni * 16 + (lane & 15);
#pragma unroll
            for (int j = 0; j < 4; ++j) {
                __hip_fp8_e4m3 q(acc[mi][ni][j]);
                Cs[(rl + j) * 128 + cl] = q.__x;
            }
        }
    }
    __syncthreads();
    // coalesced store: 64B per thread (row tid>>1, half tid&1)
    {
        int row = tid >> 1, half = tid & 1;
        int gr = m0 + row;
        if (gr < M_N) {
            const f32x4* s = (const f32x4*)(Cs + row * 128 + half * 64);
            f32x4* dgl = (f32x4*)(xw8 + (size_t)gr * FEAT + n0 + half * 64);
            dgl[0] = s[0]; dgl[1] = s[1];
            dgl[2] = s[2]; dgl[3] = s[3];
        }
    }
}

// ---- gather + epilogue + pool (fp8 rows, range [d_lo,d_hi)) --------------
__global__ __launch_bounds__(256) void gather_pool_kernel(
    const uchar* __restrict__ xw8, const int* __restrict__ csr_src,
    const int* __restrict__ row_start, const float* __restrict__ bias,
    float* __restrict__ pooled, int d_lo, int d_hi) {
    __shared__ float pool_lds[FEAT];
    int tid = threadIdx.x;
    pool_lds[tid] = 0.0f;
    __syncthreads();
    int lane = tid & 63;
    int wave = tid >> 6;
    int gw = blockIdx.x * 4 + wave;
    int nw = gridDim.x * 4;
    float b0 = bias[lane * 4 + 0], b1 = bias[lane * 4 + 1];
    float b2 = bias[lane * 4 + 2], b3 = bias[lane * 4 + 3];
    float p0 = 0.f, p1 = 0.f, p2 = 0.f, p3 = 0.f;

    for (int d = d_lo + gw; d < d_hi; d += nw) {
        int e0 = row_start[d], e1 = row_start[d + 1];
        float s0 = 0.f, s1 = 0.f, s2 = 0.f, s3 = 0.f;
        int e = e0;
        for (; e + 3 < e1; e += 4) {
            int ia = csr_src[e], ib = csr_src[e + 1];
            int ic = csr_src[e + 2], id = csr_src[e + 3];
            uint ua = *(const uint*)(xw8 + (size_t)ia * FEAT + lane * 4);
            uint ub = *(const uint*)(xw8 + (size_t)ib * FEAT + lane * 4);
            uint uc = *(const uint*)(xw8 + (size_t)ic * FEAT + lane * 4);
            uint ud = *(const uint*)(xw8 + (size_t)id * FEAT + lane * 4);
            s0 += (fp8f(ua) + fp8f(ub)) + (fp8f(uc) + fp8f(ud));
            s1 += (fp8f(ua >> 8) + fp8f(ub >> 8)) + (fp8f(uc >> 8) + fp8f(ud >> 8));
            s2 += (fp8f(ua >> 16) + fp8f(ub >> 16)) + (fp8f(uc >> 16) + fp8f(ud >> 16));
            s3 += (fp8f(ua >> 24) + fp8f(ub >> 24)) + (fp8f(uc >> 24) + fp8f(ud >> 24));
        }
        for (; e < e1; ++e) {
            int ia = csr_src[e];
            uint ua = *(const uint*)(xw8 + (size_t)ia * FEAT + lane * 4);
            s0 += fp8f(ua); s1 += fp8f(ua >> 8);
            s2 += fp8f(ua >> 16); s3 += fp8f(ua >> 24);
        }
        float ri = rsqrtf(fmaxf((float)(e1 - e0), 1.0f));
        p0 += fmaxf(s0 * ri + b0, 0.f);
        p1 += fmaxf(s1 * ri + b1, 0.f);
        p2 += fmaxf(s2 * ri + b2, 0.f);
        p3 += fmaxf(s3 * ri + b3, 0.f);
    }
    atomicAdd(&pool_lds[lane * 4 + 0], p0);
    atomicAdd(&pool_lds[lane * 4 + 1], p1);
    atomicAdd(&pool_lds[lane * 4 + 2], p2);
    atomicAdd(&pool_lds[lane * 4 + 3], p3);
    __syncthreads();
    atomicAdd(&pooled[tid], pool_lds[tid]);
}

// ---------------- (pooled/N) @ W2 + b2 -> softmax(64) ---------------------
__global__ void final_kernel(const float* __restrict__ pooled, const float* __restrict__ W2,
                             const float* __restrict__ b2, float* __restrict__ out) {
    int c = threadIdx.x;
    const float invN = 1.0f / (float)M_N;
    float acc = 0.0f;
    for (int f = 0; f < FEAT; ++f) acc += pooled[f] * W2[f * NCLS + c];
    acc = acc * invN + b2[c];
    float m = acc;
#pragma unroll
    for (int o = 32; o > 0; o >>= 1) m = fmaxf(m, __shfl_xor(m, o));
    float e = expf(acc - m);
    float s = e;
#pragma unroll
    for (int o = 32; o > 0; o >>= 1) s += __shfl_xor(s, o);
    out[c] = e / s;
}

extern "C" void kernel_launch(void* const* d_in, const int* in_sizes, int n_in,
                              void* d_out, int out_size, void* d_ws, size_t ws_size,
                              hipStream_t stream) {
    const float* x   = (const float*)d_in[0];
    const int*   src = (const int*)d_in[1];
    const int*   dst = (const int*)d_in[2];
    const float* W   = (const float*)d_in[3];
    const float* b   = (const float*)d_in[4];
    const float* W2  = (const float*)d_in[5];
    const float* b2  = (const float*)d_in[6];
    float* out = (float*)d_out;

    // workspace layout (16B-aligned sections)
    char* p = (char*)d_ws;
    uchar*  xw8      = (uchar*)p;   p += (size_t)M_N * FEAT;          // 25.6 MB
    ushort* Wt       = (ushort*)p;  p += (size_t)FEAT * FEAT * 2;     // 128 KB
    int*    cnt_out  = (int*)p;     p += (size_t)M_N * 4;             // zeroed
    int*    coarse   = (int*)p;     p += (size_t)NBKT * 4 + 8;        // zeroed
    float*  pooled   = (float*)p;   p += 1024;                        // zeroed
    int*    cbase    = (int*)p;     p += ((size_t)NBKT + 4) * 4;
    int*    ccur     = (int*)p;     p += (size_t)NBKT * 64;           // padded cursors
    int*    row_start= (int*)p;     p += ((size_t)M_N + 8) * 4;
    float*  rs_out   = (float*)p;   p += (size_t)M_N * 4;
    int2*   pairs    = (int2*)p;    p += (size_t)N_E * 8;             // 12.8 MB
    int*    csr_src  = (int*)p;     p += (size_t)N_E * 4;             // 6.4 MB

    // zero cnt_out + coarse + pooled (contiguous)
    hipMemsetAsync(cnt_out, 0, (size_t)M_N * 4 + (size_t)NBKT * 4 + 8 + 1024, stream);

    hist_kernel<<<512, 256, 0, stream>>>(src, dst, cnt_out, coarse, N_E);
    cscan_kernel<<<1, 1024, 0, stream>>>(coarse, cbase, ccur);
    rs_kernel<<<(M_N + 255) / 256, 256, 0, stream>>>(cnt_out, rs_out, M_N);
    pair_kernel<<<1024, 256, 0, stream>>>(src, dst, ccur, pairs, N_E);
    lsort_kernel<<<NBKT, 256, 0, stream>>>(pairs, cbase, csr_src, row_start);
    wt_kernel<<<(FEAT * FEAT + 255) / 256, 256, 0, stream>>>(W, Wt);
    gemm_xw_kernel<<<dim3((M_N + 127) / 128, 2), 256, 0, stream>>>(x, rs_out, Wt, xw8);
    gather_pool_kernel<<<1024, 256, 0, stream>>>(xw8, csr_src, row_start, b, pooled,
                                                 0, M_N / 2);
    gather_pool_kernel<<<1024, 256, 0, stream>>>(xw8, csr_src, row_start, b, pooled,
                                                 M_N / 2, M_N);
    final_kernel<<<1, 64, 0, stream>>>(pooled, W2, b2, out);
}